// Round 8
// baseline (8211.392 us; speedup 1.0000x reference)
//
#include <hip/hip_runtime.h>
#include <hip/hip_bf16.h>
#include <stdint.h>

#define E_ 4
#define T_ 4096
#define D_ 2048
#define H_ 8192

typedef __attribute__((ext_vector_type(8))) short bf16x8;
typedef __attribute__((ext_vector_type(4))) float f32x4;
typedef __attribute__((ext_vector_type(4))) unsigned short u16x4;

// round-to-nearest-even f32 -> bf16 bit pattern
__device__ __forceinline__ unsigned short f2bf(float f) {
    unsigned int u = __float_as_uint(f);
    u = u + 0x7fffu + ((u >> 16) & 1u);
    return (unsigned short)(u >> 16);
}

// async global->LDS, 16B per lane. LDS dest is wave-uniform base; HW adds lane*16.
__device__ __forceinline__ void async16(const unsigned short* g, unsigned short* l) {
    auto gp = (const __attribute__((address_space(1))) unsigned int*)g;
    auto lp = (__attribute__((address_space(3))) unsigned int*)l;
    __builtin_amdgcn_global_load_lds(gp, lp, 16 /*bytes*/, 0 /*offset*/, 0 /*aux*/);
}

__device__ __forceinline__ f32x4 mfma16(bf16x8 a, bf16x8 b, f32x4 c) {
    return __builtin_amdgcn_mfma_f32_16x16x32_bf16(a, b, c, 0, 0, 0);
}

// ---------------- x: f32 -> bf16 (vectorized) ----------------
__global__ void cvt_x_kernel(const float4* __restrict__ in, uint2* __restrict__ out, long n4) {
    long i = (long)blockIdx.x * blockDim.x + threadIdx.x;
    long stride = (long)gridDim.x * blockDim.x;
    for (; i < n4; i += stride) {
        float4 v = in[i];
        uint2 o;
        o.x = (unsigned)f2bf(v.x) | ((unsigned)f2bf(v.y) << 16);
        o.y = (unsigned)f2bf(v.z) | ((unsigned)f2bf(v.w) << 16);
        out[i] = o;
    }
}

// ---------------- W (R x C, f32, row-major) -> Wt (C x R, bf16) per expert ----------------
__global__ void transpose_cvt_kernel(const float* __restrict__ W, unsigned short* __restrict__ Wt,
                                     int R, int C) {
    __shared__ float tile[64][65];
    const float* Wp = W + (size_t)blockIdx.z * R * C;
    unsigned short* Wtp = Wt + (size_t)blockIdx.z * R * C;
    const int c0 = blockIdx.x * 64, r0 = blockIdx.y * 64;
    const int tc = threadIdx.x & 63;
    const int tr = threadIdx.x >> 6; // 0..3
#pragma unroll
    for (int i = 0; i < 16; ++i) {
        int r = tr * 16 + i;
        tile[r][tc] = Wp[(size_t)(r0 + r) * C + c0 + tc];
    }
    __syncthreads();
#pragma unroll
    for (int i = 0; i < 16; ++i) {
        int r = tr * 16 + i;
        Wtp[(size_t)(c0 + r) * R + r0 + tc] = f2bf(tile[tc][r]);
    }
}

// ---------------- 256x256 GEMM: C[M][N] = A[M][K] * Bt[N][K]^T (+bias) ----------------
// 8 waves (2M x 4N), per-wave 128x64 output = acc[8][4] of 16x16x32 frags.
// THIS ROUND: BK=32 -> LDS = [2 dbuf][A/B][256 rows][32 kel] bf16 = 64 KiB -> 2 blocks/CU
// (r5's 128 KiB capped occupancy at 1 block/CU; barrier drains had nothing to overlap with).
// Swizzle for 32-el rows (4 x 16B slots/row): physical slot = kgroup ^ ((row>>1)&3).
//   store side: skel = 8*((lane&3) ^ ((lane>>3)&3)) (chunk base rows are multiples of 16)
//   read  side: kel  = 8*(kq ^ ((fr>>1)&3))
// Paper-checked: each 16-lane quarter covers all 8 bank-slots x2 -> conflict-free.
// K-loop = r5's validated 2-barrier schedule; vmcnt counts halved (4 staged ops/tile).
template <int K, int OUT_MODE>
__global__ __launch_bounds__(512, 4) void gemm256_kernel(
    const unsigned short* __restrict__ A,   // [E][M][K]
    const unsigned short* __restrict__ Bt,  // [E][N][K]
    const float* __restrict__ bias,         // [E][N]
    void* __restrict__ Cout,                // [E][M][N]
    int M, int N)
{
    constexpr int BK = 32;
    constexpr int NT = K / BK;
    __shared__ __align__(16) unsigned short L[2][2][256][32]; // [dbuf][A/B][row][kel] = 64 KiB

    // ---- XCD chunk + L3 supertile remap (r5-validated) ----------------------
    const int nx = gridDim.x, ny = gridDim.y;
    const int nwg = nx * ny * gridDim.z;
    const int w = (blockIdx.z * ny + blockIdx.y) * nx + blockIdx.x;
    const int cpx = nwg >> 3;
    const int xcd = w & 7;
    const int c = w >> 3;
    const int CR = cpx / nx;
    const int GX = (nx % 16 == 0) ? 16 : nx;
    const int g = c / (GX * CR);
    const int r1 = c - g * (GX * CR);
    const int byl = r1 / GX;
    const int bxi = r1 - byl * GX;
    const int fy = xcd * CR + byl;
    const int bx = g * GX + bxi;
    const int e = fy / ny;
    const int by = fy - e * ny;

    const unsigned short* Ae = A + (size_t)e * M * K;
    const unsigned short* Be = Bt + (size_t)e * N * K;
    const int bm0 = by * 256;
    const int bn0 = bx * 256;

    const int tid = threadIdx.x;
    const int lane = tid & 63;
    const int wid = tid >> 6;     // 0..7
    const int wr = wid >> 2;      // 0..1 (M half)
    const int wc = wid & 3;       // 0..3 (N quarter)

    // ---- staging geometry: 4 async16/wave/tile; chunk = 16 rows x 32 kel = 1024 B.
    // wave wid stages rows [wid*32, wid*32+32) of each matrix: i in {0,1}.
    const int srow = lane >> 2;                            // row within 16-row chunk
    const int skel = 8 * ((lane & 3) ^ ((lane >> 3) & 3)); // pre-swizzled global k offset

    auto stageAB = [&](int t) {
        const int k0 = t * BK;
        const int s = t & 1;
#pragma unroll
        for (int i = 0; i < 2; ++i)
            async16(Be + (size_t)(bn0 + wid * 32 + i * 16 + srow) * K + k0 + skel,
                    &L[s][1][wid * 32 + i * 16][0]);
#pragma unroll
        for (int i = 0; i < 2; ++i)
            async16(Ae + (size_t)(bm0 + wid * 32 + i * 16 + srow) * K + k0 + skel,
                    &L[s][0][wid * 32 + i * 16][0]);
    };

    // ---- fragment-read geometry -------------------------------------------
    const int fr = lane & 15;
    const int kq = lane >> 4;                // 0..3 (k-group: k = kq*8 + e)
    const int kel = 8 * (kq ^ ((fr >> 1) & 3)); // swizzled element offset within row

    f32x4 acc[8][4] = {};

    // ---- prologue: stage tiles 0 and 1 (4 ops each; 8 in flight per wave)
    stageAB(0);
    stageAB(1);

    bf16x8 a[4], b[4];

    for (int t = 0; t < NT; ++t) {
        const int s = t & 1;

        // ---- tile-t data visible to all waves
        if (t == NT - 1) {
            asm volatile("s_waitcnt vmcnt(0)" ::: "memory");
        } else {
            asm volatile("s_waitcnt vmcnt(4)" ::: "memory");
        }
        __builtin_amdgcn_s_barrier();

        // ---- fragment reads: b (4) + a-lo (4)
#pragma unroll
        for (int n = 0; n < 4; ++n)
            b[n] = *(const bf16x8*)&L[s][1][wc * 64 + n * 16 + fr][kel];
#pragma unroll
        for (int m = 0; m < 4; ++m)
            a[m] = *(const bf16x8*)&L[s][0][wr * 128 + m * 16 + fr][kel];

        // ---- Q1: a-lo x all b (16 MFMA)
        __builtin_amdgcn_s_setprio(1);
#pragma unroll
        for (int m = 0; m < 4; ++m)
#pragma unroll
            for (int n = 0; n < 4; ++n)
                acc[m][n] = mfma16(a[m], b[n], acc[m][n]);
        __builtin_amdgcn_s_setprio(0);

        // ---- a-hi reads (reuse a regs)
#pragma unroll
        for (int m = 0; m < 4; ++m)
            a[m] = *(const bf16x8*)&L[s][0][wr * 128 + (m + 4) * 16 + fr][kel];

        // ---- all slot-s reads landed in registers across all waves -> slot dead
        asm volatile("s_waitcnt lgkmcnt(0)" ::: "memory");
        __builtin_amdgcn_sched_barrier(0);
        __builtin_amdgcn_s_barrier();

        // ---- stage tile t+2 into the dead slot (4 ops), pinned before Q2
        if (t + 2 < NT) stageAB(t + 2);
        __builtin_amdgcn_sched_barrier(0);

        // ---- Q2: a-hi x all b (16 MFMA) — covers stage issue + HBM latency
        __builtin_amdgcn_s_setprio(1);
#pragma unroll
        for (int m = 0; m < 4; ++m)
#pragma unroll
            for (int n = 0; n < 4; ++n)
                acc[m + 4][n] = mfma16(a[m], b[n], acc[m + 4][n]);
        __builtin_amdgcn_s_setprio(0);
    }

    // ---- epilogue: LDS-transpose to contiguous row stores (r5-validated) ----
    // acc frag layout: col = lane&15 (fr), row = (lane>>4)*4 + j.
    constexpr int ST = 260;                 // f32 stride; 2-way bank residue
    float* S = (float*)&L[0][0][0][0];      // 32*260*4 = 33280 B <= 65536 B
    const int rowq = (lane >> 4) * 4;
    const float* bp = bias + (size_t)e * N;
    const float4 bb4 = *(const float4*)(bp + bn0 + lane * 4); // this lane's 4 output cols

    unsigned short* Y = (unsigned short*)Cout + (size_t)e * M * N;
    float* O = (float*)Cout + (size_t)e * M * N;

#pragma unroll
    for (int sg = 0; sg < 8; ++sg) {
        __syncthreads();  // LDS free (K-loop done / previous stripe readout done)
        if (wr == (sg >> 2)) {
            const int sl = sg & 3;
#pragma unroll
            for (int mm = 0; mm < 2; ++mm) {
#pragma unroll
                for (int n = 0; n < 4; ++n) {
#pragma unroll
                    for (int j = 0; j < 4; ++j) {
                        S[(mm * 16 + rowq + j) * ST + wc * 64 + n * 16 + fr] =
                            acc[2 * sl + mm][n][j];
                    }
                }
            }
        }
        __syncthreads();
#pragma unroll
        for (int rr = 0; rr < 4; ++rr) {
            const int rl = wid * 4 + rr;             // row within stripe
            const int rg = bm0 + sg * 32 + rl;       // global row
            f32x4 v = *(const f32x4*)&S[rl * ST + lane * 4];
            v[0] += bb4.x; v[1] += bb4.y; v[2] += bb4.z; v[3] += bb4.w;
            if (OUT_MODE == 0) {
                u16x4 o;
                o[0] = f2bf(fmaxf(v[0], 0.0f));
                o[1] = f2bf(fmaxf(v[1], 0.0f));
                o[2] = f2bf(fmaxf(v[2], 0.0f));
                o[3] = f2bf(fmaxf(v[3], 0.0f));
                *(u16x4*)(Y + (size_t)rg * N + bn0 + lane * 4) = o;
            } else {
                *(f32x4*)(O + (size_t)rg * N + bn0 + lane * 4) = v;
            }
        }
    }
}

extern "C" void kernel_launch(void* const* d_in, const int* in_sizes, int n_in,
                              void* d_out, int out_size, void* d_ws, size_t ws_size,
                              hipStream_t stream) {
    const float* x     = (const float*)d_in[0]; // (E,T,D)
    const float* fc1_w = (const float*)d_in[1]; // (E,D,H)
    const float* fc1_b = (const float*)d_in[2]; // (E,1,H)
    const float* fc2_w = (const float*)d_in[3]; // (E,H,D)
    const float* fc2_b = (const float*)d_in[4]; // (E,1,D)
    float* out = (float*)d_out;

    const size_t n_x  = (size_t)E_ * T_ * D_;
    const size_t n_w1 = (size_t)E_ * D_ * H_;
    const size_t n_w2 = (size_t)E_ * H_ * D_;
    const size_t n_y1 = (size_t)E_ * T_ * H_;

    const size_t need = (n_x + n_w1 + n_w2 + n_y1) * sizeof(unsigned short);
    if (ws_size < need) return;

    unsigned short* xb  = (unsigned short*)d_ws;
    unsigned short* w1t = xb + n_x;    // (E,H,D)
    unsigned short* w2t = w1t + n_w1;  // (E,D,H)
    unsigned short* y1  = w2t + n_w2;  // (E,T,H)

    cvt_x_kernel<<<2048, 256, 0, stream>>>((const float4*)x, (uint2*)xb, (long)(n_x / 4));
    {
        dim3 g(H_ / 64, D_ / 64, E_);
        transpose_cvt_kernel<<<g, 256, 0, stream>>>(fc1_w, w1t, D_, H_);
    }
    {
        dim3 g(D_ / 64, H_ / 64, E_);
        transpose_cvt_kernel<<<g, 256, 0, stream>>>(fc2_w, w2t, H_, D_);
    }
    // GEMM1: y1 = relu(x @ W1 + b1), bf16 out. M=T, N=H, K=D
    {
        dim3 g(H_ / 256, T_ / 256, E_);
        gemm256_kernel<D_, 0><<<g, 512, 0, stream>>>(xb, w1t, fc1_b, (void*)y1, T_, H_);
    }
    // GEMM2: out = y1 @ W2 + b2, f32 out. M=T, N=D, K=H
    {
        dim3 g(D_ / 256, T_ / 256, E_);
        gemm256_kernel<H_, 1><<<g, 512, 0, stream>>>(y1, w2t, fc2_b, (void*)out, T_, D_);
    }
}

// Round 12
// 1214.897 us; speedup vs baseline: 6.7589x; 6.7589x over previous
//
#include <hip/hip_runtime.h>
#include <hip/hip_bf16.h>
#include <stdint.h>

#define E_ 4
#define T_ 4096
#define D_ 2048
#define H_ 8192

typedef __attribute__((ext_vector_type(8))) short bf16x8;
typedef __attribute__((ext_vector_type(4))) float f32x4;
typedef __attribute__((ext_vector_type(4))) unsigned short u16x4;

// round-to-nearest-even f32 -> bf16 bit pattern
__device__ __forceinline__ unsigned short f2bf(float f) {
    unsigned int u = __float_as_uint(f);
    u = u + 0x7fffu + ((u >> 16) & 1u);
    return (unsigned short)(u >> 16);
}

// async global->LDS, 16B per lane. LDS dest is wave-uniform base; HW adds lane*16.
__device__ __forceinline__ void async16(const unsigned short* g, unsigned short* l) {
    auto gp = (const __attribute__((address_space(1))) unsigned int*)g;
    auto lp = (__attribute__((address_space(3))) unsigned int*)l;
    __builtin_amdgcn_global_load_lds(gp, lp, 16 /*bytes*/, 0 /*offset*/, 0 /*aux*/);
}

__device__ __forceinline__ f32x4 mfma16(bf16x8 a, bf16x8 b, f32x4 c) {
    return __builtin_amdgcn_mfma_f32_16x16x32_bf16(a, b, c, 0, 0, 0);
}

// ---------------- x: f32 -> bf16 (vectorized) ----------------
__global__ void cvt_x_kernel(const float4* __restrict__ in, uint2* __restrict__ out, long n4) {
    long i = (long)blockIdx.x * blockDim.x + threadIdx.x;
    long stride = (long)gridDim.x * blockDim.x;
    for (; i < n4; i += stride) {
        float4 v = in[i];
        uint2 o;
        o.x = (unsigned)f2bf(v.x) | ((unsigned)f2bf(v.y) << 16);
        o.y = (unsigned)f2bf(v.z) | ((unsigned)f2bf(v.w) << 16);
        out[i] = o;
    }
}

// ---------------- W (R x C, f32, row-major) -> Wt (C x R, bf16) per expert ----------------
__global__ void transpose_cvt_kernel(const float* __restrict__ W, unsigned short* __restrict__ Wt,
                                     int R, int C) {
    __shared__ float tile[64][65];
    const float* Wp = W + (size_t)blockIdx.z * R * C;
    unsigned short* Wtp = Wt + (size_t)blockIdx.z * R * C;
    const int c0 = blockIdx.x * 64, r0 = blockIdx.y * 64;
    const int tc = threadIdx.x & 63;
    const int tr = threadIdx.x >> 6; // 0..3
#pragma unroll
    for (int i = 0; i < 16; ++i) {
        int r = tr * 16 + i;
        tile[r][tc] = Wp[(size_t)(r0 + r) * C + c0 + tc];
    }
    __syncthreads();
#pragma unroll
    for (int i = 0; i < 16; ++i) {
        int r = tr * 16 + i;
        Wtp[(size_t)(c0 + r) * R + r0 + tc] = f2bf(tile[tc][r]);
    }
}

// ---------------- 256x256 GEMM: C[M][N] = A[M][K] * Bt[N][K]^T (+bias) ----------------
// 8 waves (2M x 4N), per-wave 128x64 output = acc[8][4] of 16x16x32 frags. BK=64.
// LDS: 2 dbuf x {A,B} x 2 halves x [128][64] bf16 = 128 KiB. XOR swizzle (verified 0 conflicts).
// Register-neutral lifetime rotation of r5's 2-barrier loop (all fragment reads hide under
// MFMA clusters; Q1 starts each tile with zero read dependency):
//   Q1(t) [regs preloaded] ; a-hi reads ; lgkm0+bar (slot-s death) ; stage t+2 ;
//   VMCNT+bar (t+1 visible) ; Q2a ; read b01(t+1) ; Q2b ; read b23(t+1)+a-lo(t+1)
// r11 RACE FIX: at t == NT-2 no t+2 staging is issued, so only t+1's <=8 loads are
// outstanding and vmcnt(8) was a NO-OP -> last tile's fragments could be read before the
// LDS-DMA landed (absmax 1.96e-3). Use vmcnt(0) for t >= NT-2 (counted: waits exactly for
// tile t+1's loads; nothing newer is in flight).
template <int K, int OUT_MODE>
__global__ __launch_bounds__(512, 2) void gemm256_kernel(
    const unsigned short* __restrict__ A,   // [E][M][K]
    const unsigned short* __restrict__ Bt,  // [E][N][K]
    const float* __restrict__ bias,         // [E][N]
    void* __restrict__ Cout,                // [E][M][N]
    int M, int N)
{
    constexpr int BK = 64;
    constexpr int NT = K / BK;
    __shared__ __align__(16) unsigned short L[2][2][2][128][64]; // [dbuf][A/B][half][row][kel]

    // ---- XCD chunk + L3 supertile remap (r5-validated) ----------------------
    const int nx = gridDim.x, ny = gridDim.y;
    const int nwg = nx * ny * gridDim.z;
    const int w = (blockIdx.z * ny + blockIdx.y) * nx + blockIdx.x;
    const int cpx = nwg >> 3;
    const int xcd = w & 7;
    const int c = w >> 3;
    const int CR = cpx / nx;
    const int GX = (nx % 16 == 0) ? 16 : nx;
    const int g = c / (GX * CR);
    const int r1 = c - g * (GX * CR);
    const int byl = r1 / GX;
    const int bxi = r1 - byl * GX;
    const int fy = xcd * CR + byl;
    const int bx = g * GX + bxi;
    const int e = fy / ny;
    const int by = fy - e * ny;

    const unsigned short* Ae = A + (size_t)e * M * K;
    const unsigned short* Be = Bt + (size_t)e * N * K;
    const int bm0 = by * 256;
    const int bn0 = bx * 256;

    const int tid = threadIdx.x;
    const int lane = tid & 63;
    const int wid = tid >> 6;     // 0..7
    const int wr = wid >> 2;      // 0..1 (M half)
    const int wc = wid & 3;       // 0..3 (N quarter)

    // staging geometry: per call i in 0..1, rows wid*16 + i*8 + (lane>>3)
    const int srow = wid * 16 + (lane >> 3);
    const int skel = 8 * ((lane & 7) ^ (lane >> 3)); // pre-swizzled global k offset

    // fragment-read geometry
    const int fr = lane & 15;
    const int kq = lane >> 4;          // 0..3
    const int ksw = (lane & 7) << 3;   // read-side swizzle (elements)
    const int bh = wc >> 1;            // B half this wave reads
    const int brb = (wc & 1) * 64;     // B row base within half

    f32x4 acc[8][4] = {};

    auto stageA = [&](int t, int h) {
        const int k0 = t * BK;
        const int s = t & 1;
#pragma unroll
        for (int i = 0; i < 2; ++i) {
            async16(Ae + (size_t)(bm0 + h * 128 + srow + i * 8) * K + k0 + skel,
                    &L[s][0][h][wid * 16 + i * 8][0]);
        }
    };
    auto stageB = [&](int t, int h) {
        const int k0 = t * BK;
        const int s = t & 1;
#pragma unroll
        for (int i = 0; i < 2; ++i) {
            async16(Be + (size_t)(bn0 + h * 128 + srow + i * 8) * K + k0 + skel,
                    &L[s][1][h][wid * 16 + i * 8][0]);
        }
    };

    // ---- prologue: stage tiles 0 and 1 (8 loads each; 16 in flight)
    stageB(0, 0); stageB(0, 1); stageA(0, 0); stageA(0, 1);
    stageB(1, 0); stageB(1, 1); stageA(1, 0); stageA(1, 1);
    asm volatile("s_waitcnt vmcnt(8)" ::: "memory"); // tile 0 landed
    __builtin_amdgcn_sched_barrier(0);
    __builtin_amdgcn_s_barrier();

    bf16x8 a[4][2], b[4][2];
    // preload tile-0 fragments: b (8 reads) + a-lo (8 reads)
#pragma unroll
    for (int n = 0; n < 4; ++n)
#pragma unroll
        for (int kk = 0; kk < 2; ++kk)
            b[n][kk] = *(const bf16x8*)&L[0][1][bh][brb + n * 16 + fr][(kk * 32 + kq * 8) ^ ksw];
#pragma unroll
    for (int m = 0; m < 4; ++m)
#pragma unroll
        for (int kk = 0; kk < 2; ++kk)
            a[m][kk] = *(const bf16x8*)&L[0][0][wr][m * 16 + fr][(kk * 32 + kq * 8) ^ ksw];

    for (int t = 0; t < NT; ++t) {
        const int s = t & 1;

        // ---- Q1: a-lo x all b (32 MFMA); deps on preloaded regs only
        __builtin_amdgcn_s_setprio(1);
#pragma unroll
        for (int m = 0; m < 4; ++m)
#pragma unroll
            for (int n = 0; n < 4; ++n)
#pragma unroll
                for (int kk = 0; kk < 2; ++kk)
                    acc[m][n] = mfma16(a[m][kk], b[n][kk], acc[m][n]);
        __builtin_amdgcn_s_setprio(0);

        // ---- a-hi reads (reuse a regs)
#pragma unroll
        for (int m = 0; m < 4; ++m)
#pragma unroll
            for (int kk = 0; kk < 2; ++kk)
                a[m][kk] = *(const bf16x8*)&L[s][0][wr][(m + 4) * 16 + fr][(kk * 32 + kq * 8) ^ ksw];

        // ---- all slot-s reads landed across all waves -> slot s dead
        asm volatile("s_waitcnt lgkmcnt(0)" ::: "memory");
        __builtin_amdgcn_sched_barrier(0);
        __builtin_amdgcn_s_barrier();

        // ---- stage tile t+2 into the dead slot (8 gloads)
        if (t + 2 < NT) {
            stageB(t + 2, 0); stageB(t + 2, 1);
            stageA(t + 2, 0); stageA(t + 2, 1);
        }
        __builtin_amdgcn_sched_barrier(0);

        // ---- t+1 data visible. t < NT-2: 8 newer (t+2) loads in flight -> vmcnt(8).
        // t >= NT-2: NOTHING newer in flight -> must drain to 0 (r11 race fix).
        if (t >= NT - 2) {
            asm volatile("s_waitcnt vmcnt(0)" ::: "memory");
        } else {
            asm volatile("s_waitcnt vmcnt(8)" ::: "memory");
        }
        __builtin_amdgcn_sched_barrier(0);
        __builtin_amdgcn_s_barrier();

        // ---- Q2a: a-hi x b[0..1] (16 MFMA)
        __builtin_amdgcn_s_setprio(1);
#pragma unroll
        for (int m = 0; m < 4; ++m)
#pragma unroll
            for (int n = 0; n < 2; ++n)
#pragma unroll
                for (int kk = 0; kk < 2; ++kk)
                    acc[m + 4][n] = mfma16(a[m][kk], b[n][kk], acc[m + 4][n]);
        __builtin_amdgcn_s_setprio(0);

        // ---- b[0..1] dead -> read b01(t+1) from slot s^1 (4 reads, hides under Q2)
        if (t + 1 < NT) {
#pragma unroll
            for (int n = 0; n < 2; ++n)
#pragma unroll
                for (int kk = 0; kk < 2; ++kk)
                    b[n][kk] = *(const bf16x8*)&L[s ^ 1][1][bh][brb + n * 16 + fr][(kk * 32 + kq * 8) ^ ksw];
        }

        // ---- Q2b: a-hi x b[2..3] (16 MFMA)
        __builtin_amdgcn_s_setprio(1);
#pragma unroll
        for (int m = 0; m < 4; ++m)
#pragma unroll
            for (int n = 2; n < 4; ++n)
#pragma unroll
                for (int kk = 0; kk < 2; ++kk)
                    acc[m + 4][n] = mfma16(a[m][kk], b[n][kk], acc[m + 4][n]);
        __builtin_amdgcn_s_setprio(0);

        // ---- read b23(t+1) + a-lo(t+1) (12 reads; consumed by next Q1 via dep waits)
        if (t + 1 < NT) {
#pragma unroll
            for (int n = 2; n < 4; ++n)
#pragma unroll
                for (int kk = 0; kk < 2; ++kk)
                    b[n][kk] = *(const bf16x8*)&L[s ^ 1][1][bh][brb + n * 16 + fr][(kk * 32 + kq * 8) ^ ksw];
#pragma unroll
            for (int m = 0; m < 4; ++m)
#pragma unroll
                for (int kk = 0; kk < 2; ++kk)
                    a[m][kk] = *(const bf16x8*)&L[s ^ 1][0][wr][m * 16 + fr][(kk * 32 + kq * 8) ^ ksw];
        }
    }

    // ---- epilogue: LDS-transpose to contiguous row stores (r5-validated) ----
    // acc frag layout: col = lane&15 (fr), row = (lane>>4)*4 + j.
    constexpr int ST = 260;                     // f32 stride; 2-way bank residue
    float* S = (float*)&L[0][0][0][0][0];       // 32*260*4 = 33280 B
    const int rowq = (lane >> 4) * 4;
    const float* bp = bias + (size_t)e * N;
    const float4 bb4 = *(const float4*)(bp + bn0 + lane * 4); // this lane's 4 output cols

    unsigned short* Y = (unsigned short*)Cout + (size_t)e * M * N;
    float* O = (float*)Cout + (size_t)e * M * N;

#pragma unroll
    for (int sg = 0; sg < 8; ++sg) {
        __syncthreads();  // LDS free (K-loop done / previous stripe readout done)
        if (wr == (sg >> 2)) {
            const int sl = sg & 3;
#pragma unroll
            for (int mm = 0; mm < 2; ++mm) {
#pragma unroll
                for (int n = 0; n < 4; ++n) {
#pragma unroll
                    for (int j = 0; j < 4; ++j) {
                        S[(mm * 16 + rowq + j) * ST + wc * 64 + n * 16 + fr] =
                            acc[2 * sl + mm][n][j];
                    }
                }
            }
        }
        __syncthreads();
#pragma unroll
        for (int rr = 0; rr < 4; ++rr) {
            const int rl = wid * 4 + rr;             // row within stripe
            const int rg = bm0 + sg * 32 + rl;       // global row
            f32x4 v = *(const f32x4*)&S[rl * ST + lane * 4];
            v[0] += bb4.x; v[1] += bb4.y; v[2] += bb4.z; v[3] += bb4.w;
            if (OUT_MODE == 0) {
                u16x4 o;
                o[0] = f2bf(fmaxf(v[0], 0.0f));
                o[1] = f2bf(fmaxf(v[1], 0.0f));
                o[2] = f2bf(fmaxf(v[2], 0.0f));
                o[3] = f2bf(fmaxf(v[3], 0.0f));
                *(u16x4*)(Y + (size_t)rg * N + bn0 + lane * 4) = o;
            } else {
                *(f32x4*)(O + (size_t)rg * N + bn0 + lane * 4) = v;
            }
        }
    }
}

extern "C" void kernel_launch(void* const* d_in, const int* in_sizes, int n_in,
                              void* d_out, int out_size, void* d_ws, size_t ws_size,
                              hipStream_t stream) {
    const float* x     = (const float*)d_in[0]; // (E,T,D)
    const float* fc1_w = (const float*)d_in[1]; // (E,D,H)
    const float* fc1_b = (const float*)d_in[2]; // (E,1,H)
    const float* fc2_w = (const float*)d_in[3]; // (E,H,D)
    const float* fc2_b = (const float*)d_in[4]; // (E,1,D)
    float* out = (float*)d_out;

    const size_t n_x  = (size_t)E_ * T_ * D_;
    const size_t n_w1 = (size_t)E_ * D_ * H_;
    const size_t n_w2 = (size_t)E_ * H_ * D_;
    const size_t n_y1 = (size_t)E_ * T_ * H_;

    const size_t need = (n_x + n_w1 + n_w2 + n_y1) * sizeof(unsigned short);
    if (ws_size < need) return;

    unsigned short* xb  = (unsigned short*)d_ws;
    unsigned short* w1t = xb + n_x;    // (E,H,D)
    unsigned short* w2t = w1t + n_w1;  // (E,D,H)
    unsigned short* y1  = w2t + n_w2;  // (E,T,H)

    cvt_x_kernel<<<2048, 256, 0, stream>>>((const float4*)x, (uint2*)xb, (long)(n_x / 4));
    {
        dim3 g(H_ / 64, D_ / 64, E_);
        transpose_cvt_kernel<<<g, 256, 0, stream>>>(fc1_w, w1t, D_, H_);
    }
    {
        dim3 g(D_ / 64, H_ / 64, E_);
        transpose_cvt_kernel<<<g, 256, 0, stream>>>(fc2_w, w2t, H_, D_);
    }
    // GEMM1: y1 = relu(x @ W1 + b1), bf16 out. M=T, N=H, K=D
    {
        dim3 g(H_ / 256, T_ / 256, E_);
        gemm256_kernel<D_, 0><<<g, 512, 0, stream>>>(xb, w1t, fc1_b, (void*)y1, T_, H_);
    }
    // GEMM2: out = y1 @ W2 + b2, f32 out. M=T, N=D, K=H
    {
        dim3 g(D_ / 256, T_ / 256, E_);
        gemm256_kernel<H_, 1><<<g, 512, 0, stream>>>(y1, w2t, fc2_b, (void*)out, T_, D_);
    }
}